// Round 1
// 164.732 us; speedup vs baseline: 1.0191x; 1.0191x over previous
//
#include <hip/hip_runtime.h>

#define BB 8
#define CI 32
#define CO 32
#define HH 256
#define WW 256
#define HF 64
#define KX 32   // kept kx modes
#define NJ 64   // kept ky modes (0..31, 224..255)

typedef __attribute__((ext_vector_type(8))) _Float16 half8;
typedef __attribute__((ext_vector_type(4))) float f32x4;

__device__ __constant__ float PI2 = 6.28318530717958647692f;

// pk layout (element offsets, _Float16):
//  E  B-frags (stage1):  hi 0,      lo 16384
//  D  B-frags (stage5):  hi 32768,  lo 49152
//  Tf A-frags (fwd-h):   cos-hi 65536, cos-lo 81920, sin-hi 98304, sin-lo 114688
//  A2 A-frags (inv-h):   hi 131072, lo 163840
#define PK_E   0
#define PK_D   32768
#define PK_TF  65536
#define PK_A2  131072

// ---- fp32 -> f16 hi/lo split: 22 mantissa bits total, ~4 VALU ops ----
__device__ inline void splitf16(float f, _Float16& h, _Float16& l) {
    h = (_Float16)f;
    l = (_Float16)(f - (float)h);
}

// ---------------------------------------------------------------------------
// kprepw: blocks [0,384) build all twiddle tables (f16 hi/lo, MFMA-packed);
// blocks [384,640) run the MLP->spectral-weights GEMM (M=N=2048, K=64).
// The two are independent; fusing removes one serialized launch.
// ---------------------------------------------------------------------------
__global__ __launch_bounds__(256) void kprepw(const float* __restrict__ wts,
                                              const float* __restrict__ mlp,
                                              float* __restrict__ WC,
                                              _Float16* __restrict__ pk) {
    if (blockIdx.x < 384) {
        int id = blockIdx.x * 256 + threadIdx.x;    // 0..98303
        if (id < 16384) {
            // E (stage1 B-frag): n=2kx+c, k=w; val = c?-sin:cos(2pi w kx/256)
            int j = id & 7, lane = (id >> 3) & 63, nt = (id >> 9) & 3, kt = id >> 11;
            int k = kt * 32 + (lane >> 4) * 8 + j;
            int n = nt * 16 + (lane & 15);
            int kx = n >> 1, c = n & 1;
            int p = (k * kx) & 255;
            float sn, cs; sincosf(PI2 * (float)p / 256.0f, &sn, &cs);
            float val = c ? -sn : cs;
            _Float16 h, l; splitf16(val, h, l);
            pk[id] = h; pk[id + 16384] = l;
        } else if (id < 32768) {
            // D (stage5 B-frag): k=2kx+c, n=w; val = ck*(c?-sin:cos)(2pi kx w/256)
            int id2 = id - 16384;
            int j = id2 & 7, lane = (id2 >> 3) & 63, nt = (id2 >> 9) & 15, kt = id2 >> 13;
            int k = kt * 32 + (lane >> 4) * 8 + j;
            int w = nt * 16 + (lane & 15);
            int kx = k >> 1, c = k & 1;
            int p = (kx * w) & 255;
            float sn, cs; sincosf(PI2 * (float)p / 256.0f, &sn, &cs);
            float ck = (kx == 0) ? 1.0f : 2.0f;
            float val = c ? -ck * sn : ck * cs;
            _Float16 h, l; splitf16(val, h, l);
            pk[PK_D + id2] = h; pk[PK_D + 16384 + id2] = l;
        } else if (id < 65536) {
            // Tf (fwd-h A-frag): m=j, k=h; plane p: 0=cos,1=sin of 2pi ky h/256
            int idt = id - 32768;
            int e = idt & 7, lane = (idt >> 3) & 63, kt = (idt >> 9) & 7, mt = (idt >> 12) & 3, p = (idt >> 14) & 1;
            int j = mt * 16 + (lane & 15);
            int h = kt * 32 + (lane >> 4) * 8 + e;
            int ky = (j < 32) ? j : (192 + j);
            int ang = (ky * h) & 255;
            float sn, cs; sincosf(PI2 * (float)ang / 256.0f, &sn, &cs);
            float val = p ? sn : cs;
            _Float16 hh, ll; splitf16(val, hh, ll);
            int base = PK_TF + p * 32768 + mt * 4096 + kt * 512 + lane * 8 + e;
            pk[base] = hh; pk[base + 16384] = ll;
        } else {
            // A2 (inv-h A-frag): m=h, k'=kt*32+kq*8+e; j=k'&63, p=k'>>6
            int ida = id - 65536;
            int e = ida & 7, lane = (ida >> 3) & 63, kt = (ida >> 9) & 3, mt = ida >> 11;
            int h = mt * 16 + (lane & 15);
            int kp = kt * 32 + (lane >> 4) * 8 + e;
            int j = kp & 63, p = kp >> 6;
            int ky = (j < 32) ? j : (192 + j);
            int ang = (ky * h) & 255;
            float sn, cs; sincosf(PI2 * (float)ang / 256.0f, &sn, &cs);
            float val = p ? sn : cs;
            _Float16 hh, ll; splitf16(val, hh, ll);
            pk[PK_A2 + ida] = hh; pk[PK_A2 + 32768 + ida] = ll;
        }
        return;
    }

    // ---- GEMM part: WC[s][m1m2][c][io] = dot(mlp_row, weights_row), K=64 ----
    // f16 subnormal dodge: mlp scaled x8 (|.|<=1), wts scaled x4096 ([0,4)),
    // output scaled back by 1/32768.
    int t = threadIdx.x;
    int wid = t >> 6, lane = t & 63;
    int bid = blockIdx.x - 384;
    int bm = bid >> 4, bn = bid & 15;
    int m0 = bm * 128 + (wid >> 1) * 64;
    int n0 = bn * 128 + (wid & 1) * 64;
    int l15 = lane & 15, lq = lane >> 4;

    f32x4 acc[4][4];
    #pragma unroll
    for (int mt = 0; mt < 4; mt++)
        #pragma unroll
        for (int nt = 0; nt < 4; nt++)
            acc[mt][nt] = (f32x4){0.f, 0.f, 0.f, 0.f};

    #pragma unroll
    for (int kt = 0; kt < 2; kt++) {
        half8 Ah[4], Al[4];
        #pragma unroll
        for (int mt = 0; mt < 4; mt++) {
            int m = m0 + mt * 16 + l15;
            int c = m >> 10, mm = m & 1023;
            const float4* p = (const float4*)(mlp + (mm * 2 + c) * 64 + kt * 32 + lq * 8);
            float4 v0 = p[0], v1 = p[1];
            float vals[8] = {v0.x, v0.y, v0.z, v0.w, v1.x, v1.y, v1.z, v1.w};
            #pragma unroll
            for (int e = 0; e < 8; e++) {
                _Float16 h, l; splitf16(vals[e] * 8.0f, h, l);
                Ah[mt][e] = h; Al[mt][e] = l;
            }
        }
        #pragma unroll
        for (int nt = 0; nt < 4; nt++) {
            int n = n0 + nt * 16 + l15;
            int s = n >> 10, io = n & 1023;
            const float4* p = (const float4*)(wts + (io * 2 + s) * 64 + kt * 32 + lq * 8);
            float4 v0 = p[0], v1 = p[1];
            float vals[8] = {v0.x, v0.y, v0.z, v0.w, v1.x, v1.y, v1.z, v1.w};
            half8 Bh, Bl;
            #pragma unroll
            for (int e = 0; e < 8; e++) {
                _Float16 h, l; splitf16(vals[e] * 4096.0f, h, l);
                Bh[e] = h; Bl[e] = l;
            }
            #pragma unroll
            for (int mt = 0; mt < 4; mt++) {
                acc[mt][nt] = __builtin_amdgcn_mfma_f32_16x16x32_f16(Ah[mt], Bh, acc[mt][nt], 0, 0, 0);
                acc[mt][nt] = __builtin_amdgcn_mfma_f32_16x16x32_f16(Ah[mt], Bl, acc[mt][nt], 0, 0, 0);
                acc[mt][nt] = __builtin_amdgcn_mfma_f32_16x16x32_f16(Al[mt], Bh, acc[mt][nt], 0, 0, 0);
            }
        }
    }
    #pragma unroll
    for (int mt = 0; mt < 4; mt++)
        #pragma unroll
        for (int nt = 0; nt < 4; nt++)
            #pragma unroll
            for (int r = 0; r < 4; r++) {
                int m = m0 + mt * 16 + lq * 4 + r;
                int n = n0 + nt * 16 + l15;
                int addr = (((n >> 10) * 1024 + (m & 1023)) * 2 + (m >> 10)) * 1024 + (n & 1023);
                WC[addr] = acc[mt][nt][r] * (1.0f / 32768.0f);
            }
}

// ---------------------------------------------------------------------------
// kfwd (fused stages 1+2, all-MFMA): block = one (b,i) slab, 512 thr.
//  Stage 1 now streams x through LDS with double-buffered global_load_lds
//  (counted vmcnt(4), raw s_barriers -> the prefetch is never drained).
//  x tiles are XOR-swizzled at the 4-float-group level: linear LDS dest +
//  pre-swizzled GLOBAL source (per-lane src is allowed), swizzled ds_read.
//  Stage 2: C_A = cos*X, C_B = sin*X (A-frags from pk); combine via
//  shfl_xor(1):  F_re(n even) = CA + CBsw, F_im(n odd) = CA - CBsw.
// ---------------------------------------------------------------------------
#define XS_STR 264
__global__ __launch_bounds__(512) void kfwd(const float* __restrict__ x,
                                            const _Float16* __restrict__ pk,
                                            float* __restrict__ F) {
    __shared__ float xs[2][8192];               // 64 KB: 2 x [256 rows][32 floats]
    __shared__ _Float16 Xbf[2][64 * XS_STR];    // 67.6 KB
    int t = threadIdx.x;
    int bi = blockIdx.x;
    int w = t >> 6, lane = t & 63;
    int l15 = lane & 15, lq = lane >> 4;
    const float* xsl = x + ((size_t)bi << 16);

    // chunk c (0..2047): row=c>>3, dest grp gd=c&7 holds src grp gs=gd^(row&7)
#define STAGE(ktt, sel) do {                                                   \
    _Pragma("unroll")                                                          \
    for (int i_ = 0; i_ < 4; i_++) {                                           \
        int c_ = i_ * 512 + w * 64 + lane;                                     \
        int row_ = c_ >> 3;                                                    \
        int gs_ = (c_ & 7) ^ (row_ & 7);                                       \
        const float* gp_ = xsl + row_ * 256 + (ktt) * 32 + gs_ * 4;            \
        __builtin_amdgcn_global_load_lds(                                      \
            (const __attribute__((address_space(1))) unsigned int*)gp_,        \
            (__attribute__((address_space(3))) unsigned int*)&xs[sel][(i_ * 512 + w * 64) * 4], \
            16, 0, 0);                                                         \
    }                                                                          \
} while (0)

    f32x4 acc[2][4];
    #pragma unroll
    for (int mt = 0; mt < 2; mt++)
        #pragma unroll
        for (int nt = 0; nt < 4; nt++)
            acc[mt][nt] = (f32x4){0.f, 0.f, 0.f, 0.f};

    STAGE(0, 0);
    for (int kt = 0; kt < 8; kt++) {
        int sel = kt & 1;
        // E-frags for this K-tile (L2-hot); issued BEFORE the stage of kt+1 so
        // the counted vmcnt below covers them too.
        half8 Eh[4], El[4];
        #pragma unroll
        for (int nt = 0; nt < 4; nt++) {
            Eh[nt] = *(const half8*)(pk + ((size_t)((kt * 4 + nt) * 64 + lane)) * 8);
            El[nt] = *(const half8*)(pk + 16384 + ((size_t)((kt * 4 + nt) * 64 + lane)) * 8);
        }
        if (kt < 7) {
            STAGE(kt + 1, sel ^ 1);
            asm volatile("s_waitcnt vmcnt(4)" ::: "memory");   // tile kt + E landed; kt+1 in flight
        } else {
            asm volatile("s_waitcnt vmcnt(0)" ::: "memory");
        }
        __builtin_amdgcn_s_barrier();
        #pragma unroll
        for (int mt = 0; mt < 2; mt++) {
            int row = w * 32 + mt * 16 + l15;
            int g0 = (2 * lq) ^ (row & 7);
            float4 va = *(const float4*)&xs[sel][row * 32 + g0 * 4];        // cols 8lq..+3
            float4 vb = *(const float4*)&xs[sel][row * 32 + (g0 ^ 1) * 4];  // cols 8lq+4..+7
            float vals[8] = {va.x, va.y, va.z, va.w, vb.x, vb.y, vb.z, vb.w};
            half8 ah, al;
            #pragma unroll
            for (int e = 0; e < 8; e++) {
                _Float16 h, l; splitf16(vals[e], h, l);
                ah[e] = h; al[e] = l;
            }
            #pragma unroll
            for (int nt = 0; nt < 4; nt++) {
                acc[mt][nt] = __builtin_amdgcn_mfma_f32_16x16x32_f16(ah, Eh[nt], acc[mt][nt], 0, 0, 0);
                acc[mt][nt] = __builtin_amdgcn_mfma_f32_16x16x32_f16(ah, El[nt], acc[mt][nt], 0, 0, 0);
                acc[mt][nt] = __builtin_amdgcn_mfma_f32_16x16x32_f16(al, Eh[nt], acc[mt][nt], 0, 0, 0);
            }
        }
        // WAR guard: ds_reads of buf[sel] must complete before any wave's next
        // STAGE overwrites it (next iter stages into buf[sel]).
        asm volatile("s_waitcnt lgkmcnt(0)" ::: "memory");
        __builtin_amdgcn_s_barrier();
    }
#undef STAGE

    // epilogue: D-layout (row h = lq*4+r, col n = nt*16+l15) -> Xbf[n][h]
    #pragma unroll
    for (int mt = 0; mt < 2; mt++)
        #pragma unroll
        for (int nt = 0; nt < 4; nt++)
            #pragma unroll
            for (int r = 0; r < 4; r++) {
                int hrow = w * 32 + mt * 16 + lq * 4 + r;
                int n = nt * 16 + l15;
                _Float16 hh, ll; splitf16(acc[mt][nt][r], hh, ll);
                Xbf[0][n * XS_STR + hrow] = hh;
                Xbf[1][n * XS_STR + hrow] = ll;
            }
    __syncthreads();

    // ---- stage 2: wave w -> mtq = w>>1 (j-tile), ntbase = (w&1)*2 ----
    int mtq = w >> 1, ntbase = (w & 1) * 2;
    f32x4 ca[2], cb[2];
    ca[0] = (f32x4){0.f,0.f,0.f,0.f}; ca[1] = (f32x4){0.f,0.f,0.f,0.f};
    cb[0] = (f32x4){0.f,0.f,0.f,0.f}; cb[1] = (f32x4){0.f,0.f,0.f,0.f};
    #pragma unroll
    for (int kt = 0; kt < 8; kt++) {
        int aoff = PK_TF + mtq * 4096 + kt * 512 + lane * 8;
        half8 Ach = *(const half8*)(pk + aoff);
        half8 Acl = *(const half8*)(pk + aoff + 16384);
        half8 Ash = *(const half8*)(pk + aoff + 32768);
        half8 Asl = *(const half8*)(pk + aoff + 49152);
        #pragma unroll
        for (int ntl = 0; ntl < 2; ntl++) {
            int n = (ntbase + ntl) * 16 + l15;
            half8 xh = *(const half8*)&Xbf[0][n * XS_STR + kt * 32 + lq * 8];
            half8 xl = *(const half8*)&Xbf[1][n * XS_STR + kt * 32 + lq * 8];
            ca[ntl] = __builtin_amdgcn_mfma_f32_16x16x32_f16(Ach, xh, ca[ntl], 0, 0, 0);
            ca[ntl] = __builtin_amdgcn_mfma_f32_16x16x32_f16(Ach, xl, ca[ntl], 0, 0, 0);
            ca[ntl] = __builtin_amdgcn_mfma_f32_16x16x32_f16(Acl, xh, ca[ntl], 0, 0, 0);
            cb[ntl] = __builtin_amdgcn_mfma_f32_16x16x32_f16(Ash, xh, cb[ntl], 0, 0, 0);
            cb[ntl] = __builtin_amdgcn_mfma_f32_16x16x32_f16(Ash, xl, cb[ntl], 0, 0, 0);
            cb[ntl] = __builtin_amdgcn_mfma_f32_16x16x32_f16(Asl, xh, cb[ntl], 0, 0, 0);
        }
    }
    // combine + store: F_float[bi*4096 + j*64 + n]
    #pragma unroll
    for (int ntl = 0; ntl < 2; ntl++) {
        int n = (ntbase + ntl) * 16 + l15;
        #pragma unroll
        for (int r = 0; r < 4; r++) {
            float a = ca[ntl][r];
            float bsw = __shfl_xor(cb[ntl][r], 1, 64);
            float out = (n & 1) ? (a - bsw) : (a + bsw);
            int j = mtq * 16 + lq * 4 + r;
            F[(size_t)bi * 4096 + j * 64 + n] = out;
        }
    }
}

// ---------------------------------------------------------------------------
// Stage 3: mode mixing. WC layout [s][m1m2][c][io]. (1/65536 irfft scale moved
// to kinv epilogue so OM stays in f16-normal range there.)
// ---------------------------------------------------------------------------
__global__ void kmodes(const float* __restrict__ F, const float* __restrict__ WC,
                       const float* __restrict__ mod1, const float* __restrict__ mod2,
                       float* __restrict__ OM) {
    int m = blockIdx.x;             // j*32 + kx
    int j = m >> 5, kx = m & 31;
    int s = j >> 5;
    int m1 = j & 31, m2 = kx;
    __shared__ float2 fs[BB][CI];
    __shared__ float wcr[CI * CO];
    __shared__ float wci[CI * CO];
    int t = threadIdx.x;
    {
        int b = t >> 5, i = t & 31;
        fs[b][i] = ((const float2*)F)[((size_t)(b * CI + i) * NJ + j) * KX + kx];
    }
    {
        const float4* wg = (const float4*)(WC + ((size_t)(s * 1024 + m1 * 32 + m2) * 2) * 1024);
        ((float4*)wcr)[t] = wg[t];
        ((float4*)wci)[t] = wg[t + 256];
    }
    __syncthreads();
    int b = t >> 5, o = t & 31;
    float ar = 0.f, ai = 0.f;
    #pragma unroll 8
    for (int i = 0; i < CI; i++) {
        float2 f = fs[b][i];
        float wx = wcr[i * 32 + o];
        float wy = wci[i * 32 + o];
        ar = fmaf(f.x, wx, ar);
        ar = fmaf(-f.y, wy, ar);
        ai = fmaf(f.x, wy, ai);
        ai = fmaf(f.y, wx, ai);
    }
    const float* mp = (s == 0) ? mod1 : mod2;
    float mr = mp[(b * 1024 + m1 * 32 + m2) * 2 + 0];
    float mi = mp[(b * 1024 + m1 * 32 + m2) * 2 + 1];
    float outr = (ar * mr - ai * mi);
    float outi = (ar * mi + ai * mr);
    ((float2*)OM)[((size_t)(b * CO + o) * NJ + j) * KX + kx] = make_float2(outr, outi);
}

// ---------------------------------------------------------------------------
// kinv (fused stages 4+5, all-MFMA): block = one (b,o) slab, 512 thr.
//  Phase 0: OM -> B' in LDS (f16 hi/lo).
//  Phase 1: G[h][n] = A2[h][:] * B'  (M=256, K=128).
//  Phase 2: G -> LDS f16 hi/lo as A-frag layout [h][n] (stride 72).
//  Phase 3: y[h][:] = G[h][:] * D; epilogue applies the 1/65536 irfft scale.
// ---------------------------------------------------------------------------
#define BP_STR 136
#define GB_STR 72
__global__ __launch_bounds__(512) void kinv(const float* __restrict__ OM,
                                            const _Float16* __restrict__ pk,
                                            float* __restrict__ y) {
    __shared__ _Float16 smem[2 * 256 * GB_STR];    // 73.7 KB (union: B' then Gbf)
    _Float16* Bp0 = smem;                 // [64][136]
    _Float16* Bp1 = smem + 64 * BP_STR;
    _Float16* G0 = smem;                  // [256][72]
    _Float16* G1 = smem + 256 * GB_STR;
    int t = threadIdx.x;
    int bo = blockIdx.x;
    int lane = t & 63, w = t >> 6;
    int l15 = lane & 15, lq = lane >> 4;

    // ---- phase 0: build B' ----
    {
        const float4* src = (const float4*)OM + (size_t)bo * 1024;
        #pragma unroll
        for (int q = 0; q < 2; q++) {
            int idx4 = t + q * 512;            // entry pair (2*idx4, 2*idx4+1)
            float4 v = src[idx4];
            #pragma unroll
            for (int half = 0; half < 2; half++) {
                int e = idx4 * 2 + half;
                int j = e >> 5, kx = e & 31;
                float Or = half ? v.z : v.x;
                float Oi = half ? v.w : v.y;
                _Float16 orh, orl, oih, oil;
                splitf16(Or, orh, orl);
                splitf16(Oi, oih, oil);
                Bp0[(2 * kx) * BP_STR + j] = orh;           Bp1[(2 * kx) * BP_STR + j] = orl;
                Bp0[(2 * kx) * BP_STR + 64 + j] = -oih;     Bp1[(2 * kx) * BP_STR + 64 + j] = -oil;
                Bp0[(2 * kx + 1) * BP_STR + j] = oih;       Bp1[(2 * kx + 1) * BP_STR + j] = oil;
                Bp0[(2 * kx + 1) * BP_STR + 64 + j] = orh;  Bp1[(2 * kx + 1) * BP_STR + 64 + j] = orl;
            }
        }
    }
    __syncthreads();

    // ---- phase 1: G = A2 * B', wave w -> mt = w*2+{0,1}, all 4 nt ----
    f32x4 g[2][4];
    #pragma unroll
    for (int mtl = 0; mtl < 2; mtl++)
        #pragma unroll
        for (int nt = 0; nt < 4; nt++)
            g[mtl][nt] = (f32x4){0.f, 0.f, 0.f, 0.f};
    #pragma unroll
    for (int kt = 0; kt < 4; kt++) {
        half8 a2h[2], a2l[2];
        #pragma unroll
        for (int mtl = 0; mtl < 2; mtl++) {
            int mt = w * 2 + mtl;
            int aoff = PK_A2 + mt * 2048 + kt * 512 + lane * 8;
            a2h[mtl] = *(const half8*)(pk + aoff);
            a2l[mtl] = *(const half8*)(pk + aoff + 32768);
        }
        #pragma unroll
        for (int nt = 0; nt < 4; nt++) {
            int n = nt * 16 + l15;
            half8 bh = *(const half8*)&Bp0[n * BP_STR + kt * 32 + lq * 8];
            half8 bl = *(const half8*)&Bp1[n * BP_STR + kt * 32 + lq * 8];
            #pragma unroll
            for (int mtl = 0; mtl < 2; mtl++) {
                g[mtl][nt] = __builtin_amdgcn_mfma_f32_16x16x32_f16(a2h[mtl], bh, g[mtl][nt], 0, 0, 0);
                g[mtl][nt] = __builtin_amdgcn_mfma_f32_16x16x32_f16(a2h[mtl], bl, g[mtl][nt], 0, 0, 0);
                g[mtl][nt] = __builtin_amdgcn_mfma_f32_16x16x32_f16(a2l[mtl], bh, g[mtl][nt], 0, 0, 0);
            }
        }
    }
    __syncthreads();    // all B' reads done; smem becomes Gbf

    // ---- phase 2: store G as f16 hi/lo, layout [h][n] ----
    #pragma unroll
    for (int mtl = 0; mtl < 2; mtl++)
        #pragma unroll
        for (int nt = 0; nt < 4; nt++)
            #pragma unroll
            for (int r = 0; r < 4; r++) {
                int h = (w * 2 + mtl) * 16 + lq * 4 + r;
                int n = nt * 16 + l15;
                _Float16 hh, ll; splitf16(g[mtl][nt][r], hh, ll);
                G0[h * GB_STR + n] = hh;
                G1[h * GB_STR + n] = ll;
            }
    __syncthreads();

    // ---- phase 3: y = G * D, wave w -> cols nt2 = w*2+{0,1} ----
    const _Float16* pkD = pk + PK_D;
    half8 Bh[2][2], Bl[2][2];
    #pragma unroll
    for (int kt = 0; kt < 2; kt++)
        #pragma unroll
        for (int ntl = 0; ntl < 2; ntl++) {
            int nt = w * 2 + ntl;
            Bh[kt][ntl] = *(const half8*)(pkD + ((size_t)((kt * 16 + nt) * 64 + lane)) * 8);
            Bl[kt][ntl] = *(const half8*)(pkD + 16384 + ((size_t)((kt * 16 + nt) * 64 + lane)) * 8);
        }
    #pragma unroll 4
    for (int mt = 0; mt < 16; mt++) {
        f32x4 acc2[2];
        acc2[0] = (f32x4){0.f, 0.f, 0.f, 0.f};
        acc2[1] = (f32x4){0.f, 0.f, 0.f, 0.f};
        #pragma unroll
        for (int kt = 0; kt < 2; kt++) {
            half8 ah = *(const half8*)&G0[(mt * 16 + l15) * GB_STR + kt * 32 + lq * 8];
            half8 al = *(const half8*)&G1[(mt * 16 + l15) * GB_STR + kt * 32 + lq * 8];
            #pragma unroll
            for (int ntl = 0; ntl < 2; ntl++) {
                acc2[ntl] = __builtin_amdgcn_mfma_f32_16x16x32_f16(ah, Bh[kt][ntl], acc2[ntl], 0, 0, 0);
                acc2[ntl] = __builtin_amdgcn_mfma_f32_16x16x32_f16(ah, Bl[kt][ntl], acc2[ntl], 0, 0, 0);
                acc2[ntl] = __builtin_amdgcn_mfma_f32_16x16x32_f16(al, Bh[kt][ntl], acc2[ntl], 0, 0, 0);
            }
        }
        #pragma unroll
        for (int ntl = 0; ntl < 2; ntl++)
            #pragma unroll
            for (int r = 0; r < 4; r++)
                y[(size_t)(bo * 256 + mt * 16 + lq * 4 + r) * 256 + (w * 2 + ntl) * 16 + l15] =
                    acc2[ntl][r] * (1.0f / 65536.0f);
    }
}

// ---------------------------------------------------------------------------
extern "C" void kernel_launch(void* const* d_in, const int* in_sizes, int n_in,
                              void* d_out, int out_size, void* d_ws, size_t ws_size,
                              hipStream_t stream) {
    const float* x    = (const float*)d_in[0];
    const float* mod1 = (const float*)d_in[1];
    const float* mod2 = (const float*)d_in[2];
    const float* wts  = (const float*)d_in[3];
    const float* mlp  = (const float*)d_in[4];
    float* y = (float*)d_out;

    float* ws = (float*)d_ws;
    float* F  = ws;                         // 1,048,576 floats
    float* WC = F + 1048576;                // 4,194,304
    float* OM = WC + 4194304;               // 1,048,576
    _Float16* pk = (_Float16*)(OM + 1048576);   // 196,608 halves

    kprepw<<<dim3(640),  dim3(256), 0, stream>>>(wts, mlp, WC, pk);
    kfwd  <<<dim3(BB * CI), dim3(512), 0, stream>>>(x, pk, F);
    kmodes<<<dim3(NJ * KX), dim3(256), 0, stream>>>(F, WC, mod1, mod2, OM);
    kinv  <<<dim3(BB * CO), dim3(512), 0, stream>>>(OM, pk, y);
}